// Round 8
// baseline (1218.200 us; speedup 1.0000x reference)
//
#include <hip/hip_runtime.h>

// GraphSAGE: x(524288,256) -> FC relu -> 3x sage_conv -> out(8192,64)
// R8: agg_k round-robin 4 rows/wave (4 independent gather chains vs serial tail).
//     K-phased B-in-LDS MFMA GEMM (global_load_lds, pre-swizzled source), bf16
//     activations, CSR pull-aggregation.
constexpr int N0c = 524288, N1c = 262144, N2c = 65536, N3c = 8192;

typedef __attribute__((ext_vector_type(8))) short   bf16x8;
typedef __attribute__((ext_vector_type(4))) float   f32x4;
typedef __attribute__((ext_vector_type(4))) unsigned short u16x4;

__device__ inline unsigned short f2bf(float f) {
    union { float f; unsigned u; } v; v.f = f;
    unsigned r = v.u + 0x7FFF + ((v.u >> 16) & 1);   // RNE
    return (unsigned short)(r >> 16);
}
__device__ inline float bf2f(unsigned short u) {
    union { unsigned u; float f; } v; v.u = ((unsigned)u) << 16;
    return v.f;
}

__device__ inline void glds16(const void* g, void* l) {
    __builtin_amdgcn_global_load_lds(
        (const __attribute__((address_space(1))) unsigned int*)g,
        (__attribute__((address_space(3))) unsigned int*)l, 16, 0, 0);
}

// transpose + cast one weight: Wt[n][k] = bf16(W[k][n]); K is always 256 here
__global__ __launch_bounds__(256)
void wconv_k(const float* __restrict__ W, unsigned short* __restrict__ Wt, int K, int N)
{
    const int i = blockIdx.x * 256 + threadIdx.x;   // over K*N
    if (i >= K * N) return;
    const int k = i / N, n = i % N;
    Wt[n * K + k] = f2bf(W[i]);
}

__device__ inline bf16x8 pack_bf8(const float* p) {
    const f32x4 u = *(const f32x4*)p;
    const f32x4 v = *(const f32x4*)(p + 4);
    bf16x8 t;
    #pragma unroll
    for (int j = 0; j < 4; ++j) {
        t[j]     = (short)f2bf(u[j]);
        t[j + 4] = (short)f2bf(v[j]);
    }
    return t;
}

// C[M x N] = act( A1 @ Wt1^T (+ A2 @ Wt2^T) + b ), K=256, N=NT*16.
// 512 thr = 8 waves, wave owns one 16-row strip (acc = NT*4 regs, persistent).
// Per phase: stage KC cols of W1 (and W2 if DUAL) into 64KB LDS via
// global_load_lds with pre-swizzled source; compute; barrier; restage.
template<int NT, int KC, bool DUAL, bool RELU, bool A_F32, bool OUT_BF16>
__global__ __launch_bounds__(512, 2)
void gemm2(const void* __restrict__ A1v, const void* __restrict__ A2v,
           const unsigned short* __restrict__ Wt1,
           const unsigned short* __restrict__ Wt2,
           const float* __restrict__ bias, void* __restrict__ Cv)
{
    constexpr int N     = NT * 16;
    constexpr int PH    = 256 / KC;                  // phases
    constexpr int SLOTS = KC / 8;                    // 16B granules per row-chunk
    constexpr int GPM   = N * SLOTS;                 // granules per matrix/phase
    constexpr int TOTG  = GPM * (DUAL ? 2 : 1);      // == 4096 (64 KB)
    static_assert(TOTG == 4096, "LDS sizing");
    __shared__ unsigned short Bs[TOTG * 8];

    const int t    = threadIdx.x;
    const int lane = t & 63;
    const int wv   = t >> 6;                 // 0..7
    const int col  = lane & 15;              // B col-in-tile / A row-in-strip
    const int kg   = lane >> 4;              // k-group
    const int swz  = (col & 7) << 3;         // read-side XOR (ushort units)
    const long row0 = (long)blockIdx.x * 128 + wv * 16;

    const unsigned short* A1h = (const unsigned short*)A1v;
    const float*          A1f = (const float*)A1v;
    const unsigned short* A2h = (const unsigned short*)A2v;

    f32x4 acc[NT];
    #pragma unroll
    for (int nt = 0; nt < NT; ++nt) acc[nt] = (f32x4){0.f, 0.f, 0.f, 0.f};

    const long ar = (row0 + col) * 256;

    for (int kh = 0; kh < PH; ++kh) {
        if (kh) __syncthreads();             // prior phase's LDS reads done
        // ---- stage: linear LDS dest, pre-swizzled global source ----
        #pragma unroll
        for (int it = 0; it < TOTG / 512; ++it) {    // 8 iters, 1KB/wave each
            const int g  = it * 512 + t;             // granule id
            const int m  = DUAL ? (g / GPM) : 0;
            const int gm = DUAL ? (g % GPM) : g;
            const int n  = gm / SLOTS;
            const int s  = gm % SLOTS;
            const int ss = s ^ (n & 7);              // involution swizzle
            const unsigned short* srcb =
                (m ? Wt2 : Wt1) + n * 256 + kh * KC + ss * 8;
            glds16(srcb, &Bs[(it * 512 + wv * 64) * 8]);
        }
        __syncthreads();                     // drains vmcnt(0)

        #pragma unroll
        for (int k0 = 0; k0 < KC; k0 += 32) {
            const int kx = (k0 + kg * 8) ^ swz;
            const long ac = ar + kh * KC + k0 + kg * 8;
            bf16x8 a1, a2;
            if constexpr (A_F32) a1 = pack_bf8(&A1f[ac]);
            else                 a1 = *(const bf16x8*)&A1h[ac];
            if constexpr (DUAL)  a2 = *(const bf16x8*)&A2h[ac];
            #pragma unroll
            for (int nt = 0; nt < NT; ++nt) {
                const bf16x8 b1 = *(const bf16x8*)&Bs[(nt * 16 + col) * KC + kx];
                acc[nt] = __builtin_amdgcn_mfma_f32_16x16x32_bf16(a1, b1, acc[nt], 0, 0, 0);
                if constexpr (DUAL) {
                    const bf16x8 b2 = *(const bf16x8*)&Bs[GPM * 8 + (nt * 16 + col) * KC + kx];
                    acc[nt] = __builtin_amdgcn_mfma_f32_16x16x32_bf16(a2, b2, acc[nt], 0, 0, 0);
                }
            }
        }
    }

    // ---- epilogue ----
    #pragma unroll
    for (int nt = 0; nt < NT; ++nt) {
        const int c = nt * 16 + col;
        const float bb = bias[c];
        #pragma unroll
        for (int rr = 0; rr < 4; ++rr) {
            const long row = row0 + kg * 4 + rr;
            float o = acc[nt][rr] + bb;
            if constexpr (RELU) o = fmaxf(o, 0.f);
            if constexpr (OUT_BF16)
                ((unsigned short*)Cv)[row * N + c] = f2bf(o);
            else
                ((float*)Cv)[row * N + c] = o;
        }
    }
}

// ---- CSR build: counting sort of edges by dst ----

__global__ __launch_bounds__(256)
void hist_k(const int* __restrict__ dst, int* __restrict__ hist, int E)
{
    const int i = blockIdx.x * 256 + threadIdx.x;
    if (i < E) atomicAdd(&hist[dst[i]], 1);
}

__global__ __launch_bounds__(256)
void scan1_k(const int* __restrict__ hist, int* __restrict__ offs,
             int* __restrict__ bsum, int n)
{
    __shared__ int sm[256];
    const int t = threadIdx.x;
    const int base = blockIdx.x * 1024 + t * 4;
    int4 v = make_int4(0, 0, 0, 0);
    if (base < n) v = *(const int4*)&hist[base];
    const int s = v.x + v.y + v.z + v.w;
    int val = s;
    sm[t] = val; __syncthreads();
    #pragma unroll
    for (int off = 1; off < 256; off <<= 1) {
        const int add = (t >= off) ? sm[t - off] : 0;
        __syncthreads();
        val += add;
        sm[t] = val;
        __syncthreads();
    }
    const int excl = val - s;
    if (base < n) {
        offs[base]     = excl;
        offs[base + 1] = excl + v.x;
        offs[base + 2] = excl + v.x + v.y;
        offs[base + 3] = excl + v.x + v.y + v.z;
    }
    if (t == 255) bsum[blockIdx.x] = val;
}

__global__ __launch_bounds__(256)
void scan2_k(int* __restrict__ bsum, int nb)
{
    __shared__ int sm[256];
    const int t = threadIdx.x;
    const int s = (t < nb) ? bsum[t] : 0;
    int val = s;
    sm[t] = val; __syncthreads();
    #pragma unroll
    for (int off = 1; off < 256; off <<= 1) {
        const int add = (t >= off) ? sm[t - off] : 0;
        __syncthreads();
        val += add;
        sm[t] = val;
        __syncthreads();
    }
    if (t < nb) bsum[t] = val - s;
}

__global__ __launch_bounds__(256)
void scan3_k(int* __restrict__ offs, const int* __restrict__ bsum)
{
    const int i = blockIdx.x * 256 + threadIdx.x;
    offs[i] += bsum[i >> 10];
}

__global__ __launch_bounds__(256)
void fill_k(const int* __restrict__ src, const int* __restrict__ dst,
            const int* __restrict__ offs, int* __restrict__ hist,
            int* __restrict__ ssrc, int E)
{
    const int i = blockIdx.x * 256 + threadIdx.x;
    if (i < E) {
        const int d = dst[i];
        const int p = atomicAdd(&hist[d], -1) - 1;
        ssrc[offs[d] + p] = src[i];
    }
}

// 4 dst rows per wave, round-robin: 4 independent gather chains in flight.
// All loop state (j/e) is wave-uniform -> scalar branches, no divergence.
__global__ __launch_bounds__(256)
void agg_k(const unsigned short* __restrict__ h, const int* __restrict__ ssrc,
           const int* __restrict__ offs, unsigned short* __restrict__ agg,
           int n, int E)
{
    const int wid  = blockIdx.x * 4 + (threadIdx.x >> 6);
    const int lane = threadIdx.x & 63;
    const int r0   = wid * 4;
    if (r0 >= n) return;

    int j[4], e[4], deg[4];
    float acc[4][4];
    u16x4 v[4];
    #pragma unroll
    for (int r = 0; r < 4; ++r) {
        const int row = r0 + r;
        j[r] = (row < n) ? offs[row] : 0;
        e[r] = (row < n) ? ((row == n - 1) ? E : offs[row + 1]) : 0;
        deg[r] = e[r] - j[r];
        #pragma unroll
        for (int c = 0; c < 4; ++c) acc[r][c] = 0.f;
        if (j[r] < e[r])
            v[r] = *(const u16x4*)&h[(size_t)ssrc[j[r]] * 256 + lane * 4];
    }

    bool any = (j[0] < e[0]) | (j[1] < e[1]) | (j[2] < e[2]) | (j[3] < e[3]);
    while (any) {
        any = false;
        #pragma unroll
        for (int r = 0; r < 4; ++r) {
            if (j[r] < e[r]) {
                const u16x4 cur = v[r];
                const int jn = j[r] + 1;
                if (jn < e[r])                      // prefetch next edge's row
                    v[r] = *(const u16x4*)&h[(size_t)ssrc[jn] * 256 + lane * 4];
                j[r] = jn;
                #pragma unroll
                for (int c = 0; c < 4; ++c) acc[r][c] += bf2f(cur[c]);
                any |= (jn < e[r]);
            }
        }
    }

    #pragma unroll
    for (int r = 0; r < 4; ++r) {
        const int row = r0 + r;
        if (row < n) {
            const float inv = 1.0f / fmaxf((float)deg[r], 1.0f);
            u16x4 o;
            #pragma unroll
            for (int c = 0; c < 4; ++c) o[c] = f2bf(acc[r][c] * inv);
            *(u16x4*)&agg[(size_t)row * 256 + lane * 4] = o;
        }
    }
}

static void build_and_aggregate(const unsigned short* h, const int* src, const int* dst,
                                int n, int E, int* hist, int* offs, int* bsum,
                                int* ssrc, unsigned short* agg, hipStream_t stream)
{
    const dim3 blk(256);
    hipMemsetAsync(hist, 0, (size_t)n * 4, stream);
    hist_k<<<dim3((E + 255) / 256), blk, 0, stream>>>(dst, hist, E);
    scan1_k<<<dim3(n / 1024), blk, 0, stream>>>(hist, offs, bsum, n);
    scan2_k<<<dim3(1), blk, 0, stream>>>(bsum, n / 1024);
    scan3_k<<<dim3(n / 256), blk, 0, stream>>>(offs, bsum);
    fill_k<<<dim3((E + 255) / 256), blk, 0, stream>>>(src, dst, offs, hist, ssrc, E);
    agg_k<<<dim3(n / 16), blk, 0, stream>>>(h, ssrc, offs, agg, n, E);
}

extern "C" void kernel_launch(void* const* d_in, const int* in_sizes, int n_in,
                              void* d_out, int out_size, void* d_ws, size_t ws_size,
                              hipStream_t stream)
{
    const float* x    = (const float*)d_in[0];
    const int*   src0 = (const int*)d_in[1];
    const int*   dst0 = (const int*)d_in[2];
    const int*   src1 = (const int*)d_in[3];
    const int*   dst1 = (const int*)d_in[4];
    const int*   src2 = (const int*)d_in[5];
    const int*   dst2 = (const int*)d_in[6];
    const float* Wfc  = (const float*)d_in[10];
    const float* bfc  = (const float*)d_in[11];
    const float* Ws0  = (const float*)d_in[12];
    const float* Wn0  = (const float*)d_in[13];
    const float* b0   = (const float*)d_in[14];
    const float* Ws1  = (const float*)d_in[15];
    const float* Wn1  = (const float*)d_in[16];
    const float* b1   = (const float*)d_in[17];
    const float* Ws2  = (const float*)d_in[18];
    const float* Wn2  = (const float*)d_in[19];
    const float* b2   = (const float*)d_in[20];
    const int E0 = in_sizes[1], E1 = in_sizes[3], E2 = in_sizes[5];

    char* ws = (char*)d_ws;
    unsigned short* h0   = (unsigned short*)ws;                    // 256 MiB
    unsigned short* h1   = (unsigned short*)(ws + (256ULL << 20)); // 128 MiB
    unsigned short* h2   = (unsigned short*)(ws + (384ULL << 20)); //  32 MiB
    unsigned short* agg  = (unsigned short*)(ws + (416ULL << 20)); // 128 MiB
    unsigned short* Wt   = (unsigned short*)(ws + (544ULL << 20)); //   1 MiB
    int*            hist = (int*)(ws + (545ULL << 20));            //   1 MiB
    int*            offs = (int*)(ws + (546ULL << 20));            //   1 MiB
    int*            bsum = (int*)(ws + (547ULL << 20));            //   4 KiB
    int*            ssrc = (int*)(ws + (548ULL << 20));            // <=10.5 MiB

    unsigned short* wfc = Wt;
    unsigned short* ws0 = Wt + 65536;
    unsigned short* wn0 = Wt + 131072;
    unsigned short* ws1 = Wt + 196608;
    unsigned short* wn1 = Wt + 262144;
    unsigned short* ws2 = Wt + 327680;
    unsigned short* wn2 = Wt + 344064;

    const dim3 blk(256);

    // weights -> bf16 transposed [N][K]
    wconv_k<<<dim3(256), blk, 0, stream>>>(Wfc, wfc, 256, 256);
    wconv_k<<<dim3(256), blk, 0, stream>>>(Ws0, ws0, 256, 256);
    wconv_k<<<dim3(256), blk, 0, stream>>>(Wn0, wn0, 256, 256);
    wconv_k<<<dim3(256), blk, 0, stream>>>(Ws1, ws1, 256, 256);
    wconv_k<<<dim3(256), blk, 0, stream>>>(Wn1, wn1, 256, 256);
    wconv_k<<<dim3(64),  blk, 0, stream>>>(Ws2, ws2, 256, 64);
    wconv_k<<<dim3(64),  blk, 0, stream>>>(Wn2, wn2, 256, 64);

    // h0 = relu(x @ Wfc + bfc)   [f32 in, bf16 out]  128 rows/block
    gemm2<16, 128, false, true, true, true><<<dim3(N0c / 128), dim3(512), 0, stream>>>(
        x, nullptr, wfc, nullptr, bfc, h0);

    // ---- layer 0 ----
    build_and_aggregate(h0, src0, dst0, N1c, E0, hist, offs, bsum, ssrc, agg, stream);
    gemm2<16, 64, true, true, false, true><<<dim3(N1c / 128), dim3(512), 0, stream>>>(
        h0, agg, ws0, wn0, b0, h1);

    // ---- layer 1 ----
    build_and_aggregate(h1, src1, dst1, N2c, E1, hist, offs, bsum, ssrc, agg, stream);
    gemm2<16, 64, true, true, false, true><<<dim3(N2c / 128), dim3(512), 0, stream>>>(
        h1, agg, ws1, wn1, b1, h2);

    // ---- layer 2: out width 64, f32 out, no relu ----
    build_and_aggregate(h2, src2, dst2, N3c, E2, hist, offs, bsum, ssrc, agg, stream);
    gemm2<4, 256, true, false, false, false><<<dim3(N3c / 128), dim3(512), 0, stream>>>(
        h2, agg, ws2, wn2, b2, (float*)d_out);
}

// Round 9
// 984.520 us; speedup vs baseline: 1.2374x; 1.2374x over previous
//
#include <hip/hip_runtime.h>

// GraphSAGE: x(524288,256) -> FC relu -> 3x sage_conv -> out(8192,64)
// R9: agg_k = half-wave 16B gathers, masked 16-edge batches (8 loads in flight,
//     no serial tail). K-phased B-in-LDS MFMA GEMM (global_load_lds, pre-swizzled
//     source), bf16 activations, CSR pull-aggregation.
constexpr int N0c = 524288, N1c = 262144, N2c = 65536, N3c = 8192;

typedef __attribute__((ext_vector_type(8))) short   bf16x8;
typedef __attribute__((ext_vector_type(4))) float   f32x4;
typedef __attribute__((ext_vector_type(4))) unsigned short u16x4;
typedef __attribute__((ext_vector_type(8))) unsigned short u16x8;

__device__ inline unsigned short f2bf(float f) {
    union { float f; unsigned u; } v; v.f = f;
    unsigned r = v.u + 0x7FFF + ((v.u >> 16) & 1);   // RNE
    return (unsigned short)(r >> 16);
}
__device__ inline float bf2f(unsigned short u) {
    union { unsigned u; float f; } v; v.u = ((unsigned)u) << 16;
    return v.f;
}

__device__ inline void glds16(const void* g, void* l) {
    __builtin_amdgcn_global_load_lds(
        (const __attribute__((address_space(1))) unsigned int*)g,
        (__attribute__((address_space(3))) unsigned int*)l, 16, 0, 0);
}

// transpose + cast one weight: Wt[n][k] = bf16(W[k][n]); K is always 256 here
__global__ __launch_bounds__(256)
void wconv_k(const float* __restrict__ W, unsigned short* __restrict__ Wt, int K, int N)
{
    const int i = blockIdx.x * 256 + threadIdx.x;   // over K*N
    if (i >= K * N) return;
    const int k = i / N, n = i % N;
    Wt[n * K + k] = f2bf(W[i]);
}

__device__ inline bf16x8 pack_bf8(const float* p) {
    const f32x4 u = *(const f32x4*)p;
    const f32x4 v = *(const f32x4*)(p + 4);
    bf16x8 t;
    #pragma unroll
    for (int j = 0; j < 4; ++j) {
        t[j]     = (short)f2bf(u[j]);
        t[j + 4] = (short)f2bf(v[j]);
    }
    return t;
}

// C[M x N] = act( A1 @ Wt1^T (+ A2 @ Wt2^T) + b ), K=256, N=NT*16.
// 512 thr = 8 waves, wave owns one 16-row strip (acc = NT*4 regs, persistent).
// Per phase: stage KC cols of W1 (and W2 if DUAL) into 64KB LDS via
// global_load_lds with pre-swizzled source; compute; barrier; restage.
template<int NT, int KC, bool DUAL, bool RELU, bool A_F32, bool OUT_BF16>
__global__ __launch_bounds__(512, 2)
void gemm2(const void* __restrict__ A1v, const void* __restrict__ A2v,
           const unsigned short* __restrict__ Wt1,
           const unsigned short* __restrict__ Wt2,
           const float* __restrict__ bias, void* __restrict__ Cv)
{
    constexpr int N     = NT * 16;
    constexpr int PH    = 256 / KC;                  // phases
    constexpr int SLOTS = KC / 8;                    // 16B granules per row-chunk
    constexpr int GPM   = N * SLOTS;                 // granules per matrix/phase
    constexpr int TOTG  = GPM * (DUAL ? 2 : 1);      // == 4096 (64 KB)
    static_assert(TOTG == 4096, "LDS sizing");
    __shared__ unsigned short Bs[TOTG * 8];

    const int t    = threadIdx.x;
    const int lane = t & 63;
    const int wv   = t >> 6;                 // 0..7
    const int col  = lane & 15;              // B col-in-tile / A row-in-strip
    const int kg   = lane >> 4;              // k-group
    const int swz  = (col & 7) << 3;         // read-side XOR (ushort units)
    const long row0 = (long)blockIdx.x * 128 + wv * 16;

    const unsigned short* A1h = (const unsigned short*)A1v;
    const float*          A1f = (const float*)A1v;
    const unsigned short* A2h = (const unsigned short*)A2v;

    f32x4 acc[NT];
    #pragma unroll
    for (int nt = 0; nt < NT; ++nt) acc[nt] = (f32x4){0.f, 0.f, 0.f, 0.f};

    const long ar = (row0 + col) * 256;

    for (int kh = 0; kh < PH; ++kh) {
        if (kh) __syncthreads();             // prior phase's LDS reads done
        // ---- stage: linear LDS dest, pre-swizzled global source ----
        #pragma unroll
        for (int it = 0; it < TOTG / 512; ++it) {    // 8 iters, 1KB/wave each
            const int g  = it * 512 + t;             // granule id
            const int m  = DUAL ? (g / GPM) : 0;
            const int gm = DUAL ? (g % GPM) : g;
            const int n  = gm / SLOTS;
            const int s  = gm % SLOTS;
            const int ss = s ^ (n & 7);              // involution swizzle
            const unsigned short* srcb =
                (m ? Wt2 : Wt1) + n * 256 + kh * KC + ss * 8;
            glds16(srcb, &Bs[(it * 512 + wv * 64) * 8]);
        }
        __syncthreads();                     // drains vmcnt(0)

        #pragma unroll
        for (int k0 = 0; k0 < KC; k0 += 32) {
            const int kx = (k0 + kg * 8) ^ swz;
            const long ac = ar + kh * KC + k0 + kg * 8;
            bf16x8 a1, a2;
            if constexpr (A_F32) a1 = pack_bf8(&A1f[ac]);
            else                 a1 = *(const bf16x8*)&A1h[ac];
            if constexpr (DUAL)  a2 = *(const bf16x8*)&A2h[ac];
            #pragma unroll
            for (int nt = 0; nt < NT; ++nt) {
                const bf16x8 b1 = *(const bf16x8*)&Bs[(nt * 16 + col) * KC + kx];
                acc[nt] = __builtin_amdgcn_mfma_f32_16x16x32_bf16(a1, b1, acc[nt], 0, 0, 0);
                if constexpr (DUAL) {
                    const bf16x8 b2 = *(const bf16x8*)&Bs[GPM * 8 + (nt * 16 + col) * KC + kx];
                    acc[nt] = __builtin_amdgcn_mfma_f32_16x16x32_bf16(a2, b2, acc[nt], 0, 0, 0);
                }
            }
        }
    }

    // ---- epilogue ----
    #pragma unroll
    for (int nt = 0; nt < NT; ++nt) {
        const int c = nt * 16 + col;
        const float bb = bias[c];
        #pragma unroll
        for (int rr = 0; rr < 4; ++rr) {
            const long row = row0 + kg * 4 + rr;
            float o = acc[nt][rr] + bb;
            if constexpr (RELU) o = fmaxf(o, 0.f);
            if constexpr (OUT_BF16)
                ((unsigned short*)Cv)[row * N + c] = f2bf(o);
            else
                ((float*)Cv)[row * N + c] = o;
        }
    }
}

// ---- CSR build: counting sort of edges by dst ----

__global__ __launch_bounds__(256)
void hist_k(const int* __restrict__ dst, int* __restrict__ hist, int E)
{
    const int i = blockIdx.x * 256 + threadIdx.x;
    if (i < E) atomicAdd(&hist[dst[i]], 1);
}

__global__ __launch_bounds__(256)
void scan1_k(const int* __restrict__ hist, int* __restrict__ offs,
             int* __restrict__ bsum, int n)
{
    __shared__ int sm[256];
    const int t = threadIdx.x;
    const int base = blockIdx.x * 1024 + t * 4;
    int4 v = make_int4(0, 0, 0, 0);
    if (base < n) v = *(const int4*)&hist[base];
    const int s = v.x + v.y + v.z + v.w;
    int val = s;
    sm[t] = val; __syncthreads();
    #pragma unroll
    for (int off = 1; off < 256; off <<= 1) {
        const int add = (t >= off) ? sm[t - off] : 0;
        __syncthreads();
        val += add;
        sm[t] = val;
        __syncthreads();
    }
    const int excl = val - s;
    if (base < n) {
        offs[base]     = excl;
        offs[base + 1] = excl + v.x;
        offs[base + 2] = excl + v.x + v.y;
        offs[base + 3] = excl + v.x + v.y + v.z;
    }
    if (t == 255) bsum[blockIdx.x] = val;
}

__global__ __launch_bounds__(256)
void scan2_k(int* __restrict__ bsum, int nb)
{
    __shared__ int sm[256];
    const int t = threadIdx.x;
    const int s = (t < nb) ? bsum[t] : 0;
    int val = s;
    sm[t] = val; __syncthreads();
    #pragma unroll
    for (int off = 1; off < 256; off <<= 1) {
        const int add = (t >= off) ? sm[t - off] : 0;
        __syncthreads();
        val += add;
        sm[t] = val;
        __syncthreads();
    }
    if (t < nb) bsum[t] = val - s;
}

__global__ __launch_bounds__(256)
void scan3_k(int* __restrict__ offs, const int* __restrict__ bsum)
{
    const int i = blockIdx.x * 256 + threadIdx.x;
    offs[i] += bsum[i >> 10];
}

__global__ __launch_bounds__(256)
void fill_k(const int* __restrict__ src, const int* __restrict__ dst,
            const int* __restrict__ offs, int* __restrict__ hist,
            int* __restrict__ ssrc, int E)
{
    const int i = blockIdx.x * 256 + threadIdx.x;
    if (i < E) {
        const int d = dst[i];
        const int p = atomicAdd(&hist[d], -1) - 1;
        ssrc[offs[d] + p] = src[i];
    }
}

// one wave per dst row. Half-wave (32 lanes) covers a 512B row via u16x8;
// the two halves process edge pairs. Masked 16-edge batches keep 8 gathers
// in flight with NO serial tail (invalid slots re-read end-1's row: L1 dup).
__global__ __launch_bounds__(256)
void agg_k(const unsigned short* __restrict__ h, const int* __restrict__ ssrc,
           const int* __restrict__ offs, unsigned short* __restrict__ agg,
           int n, int E)
{
    const int w    = blockIdx.x * 4 + (threadIdx.x >> 6);
    const int lane = threadIdx.x & 63;
    if (w >= n) return;
    const int beg = offs[w];
    const int end = (w == n - 1) ? E : offs[w + 1];
    const int hf  = lane >> 5;           // edge parity handled by this half
    const int co  = (lane & 31) * 8;     // component offset (8 ushorts)

    float acc[8] = {0.f, 0.f, 0.f, 0.f, 0.f, 0.f, 0.f, 0.f};

    for (int j = beg; j < end; j += 16) {
        u16x8 v[8];
        bool  ok[8];
        #pragma unroll
        for (int q = 0; q < 8; ++q) {            // issue all 8 gathers first
            const int e  = j + 2 * q + hf;
            ok[q] = (e < end);
            const int es = ok[q] ? e : (end - 1);
            v[q] = *(const u16x8*)&h[(size_t)ssrc[es] * 256 + co];
        }
        #pragma unroll
        for (int q = 0; q < 8; ++q)
            #pragma unroll
            for (int c = 0; c < 8; ++c)
                acc[c] += ok[q] ? bf2f(v[q][c]) : 0.0f;
    }

    #pragma unroll
    for (int c = 0; c < 8; ++c) acc[c] += __shfl_xor(acc[c], 32);

    if (hf == 0) {                               // lanes 0..31 write the row
        const float inv = 1.0f / fmaxf((float)(end - beg), 1.0f);
        u16x8 o;
        #pragma unroll
        for (int c = 0; c < 8; ++c) o[c] = f2bf(acc[c] * inv);
        *(u16x8*)&agg[(size_t)w * 256 + co] = o;
    }
}

static void build_and_aggregate(const unsigned short* h, const int* src, const int* dst,
                                int n, int E, int* hist, int* offs, int* bsum,
                                int* ssrc, unsigned short* agg, hipStream_t stream)
{
    const dim3 blk(256);
    hipMemsetAsync(hist, 0, (size_t)n * 4, stream);
    hist_k<<<dim3((E + 255) / 256), blk, 0, stream>>>(dst, hist, E);
    scan1_k<<<dim3(n / 1024), blk, 0, stream>>>(hist, offs, bsum, n);
    scan2_k<<<dim3(1), blk, 0, stream>>>(bsum, n / 1024);
    scan3_k<<<dim3(n / 256), blk, 0, stream>>>(offs, bsum);
    fill_k<<<dim3((E + 255) / 256), blk, 0, stream>>>(src, dst, offs, hist, ssrc, E);
    agg_k<<<dim3(n / 4), blk, 0, stream>>>(h, ssrc, offs, agg, n, E);
}

extern "C" void kernel_launch(void* const* d_in, const int* in_sizes, int n_in,
                              void* d_out, int out_size, void* d_ws, size_t ws_size,
                              hipStream_t stream)
{
    const float* x    = (const float*)d_in[0];
    const int*   src0 = (const int*)d_in[1];
    const int*   dst0 = (const int*)d_in[2];
    const int*   src1 = (const int*)d_in[3];
    const int*   dst1 = (const int*)d_in[4];
    const int*   src2 = (const int*)d_in[5];
    const int*   dst2 = (const int*)d_in[6];
    const float* Wfc  = (const float*)d_in[10];
    const float* bfc  = (const float*)d_in[11];
    const float* Ws0  = (const float*)d_in[12];
    const float* Wn0  = (const float*)d_in[13];
    const float* b0   = (const float*)d_in[14];
    const float* Ws1  = (const float*)d_in[15];
    const float* Wn1  = (const float*)d_in[16];
    const float* b1   = (const float*)d_in[17];
    const float* Ws2  = (const float*)d_in[18];
    const float* Wn2  = (const float*)d_in[19];
    const float* b2   = (const float*)d_in[20];
    const int E0 = in_sizes[1], E1 = in_sizes[3], E2 = in_sizes[5];

    char* ws = (char*)d_ws;
    unsigned short* h0   = (unsigned short*)ws;                    // 256 MiB
    unsigned short* h1   = (unsigned short*)(ws + (256ULL << 20)); // 128 MiB
    unsigned short* h2   = (unsigned short*)(ws + (384ULL << 20)); //  32 MiB
    unsigned short* agg  = (unsigned short*)(ws + (416ULL << 20)); // 128 MiB
    unsigned short* Wt   = (unsigned short*)(ws + (544ULL << 20)); //   1 MiB
    int*            hist = (int*)(ws + (545ULL << 20));            //   1 MiB
    int*            offs = (int*)(ws + (546ULL << 20));            //   1 MiB
    int*            bsum = (int*)(ws + (547ULL << 20));            //   4 KiB
    int*            ssrc = (int*)(ws + (548ULL << 20));            // <=10.5 MiB

    unsigned short* wfc = Wt;
    unsigned short* ws0 = Wt + 65536;
    unsigned short* wn0 = Wt + 131072;
    unsigned short* ws1 = Wt + 196608;
    unsigned short* wn1 = Wt + 262144;
    unsigned short* ws2 = Wt + 327680;
    unsigned short* wn2 = Wt + 344064;

    const dim3 blk(256);

    // weights -> bf16 transposed [N][K]
    wconv_k<<<dim3(256), blk, 0, stream>>>(Wfc, wfc, 256, 256);
    wconv_k<<<dim3(256), blk, 0, stream>>>(Ws0, ws0, 256, 256);
    wconv_k<<<dim3(256), blk, 0, stream>>>(Wn0, wn0, 256, 256);
    wconv_k<<<dim3(256), blk, 0, stream>>>(Ws1, ws1, 256, 256);
    wconv_k<<<dim3(256), blk, 0, stream>>>(Wn1, wn1, 256, 256);
    wconv_k<<<dim3(64),  blk, 0, stream>>>(Ws2, ws2, 256, 64);
    wconv_k<<<dim3(64),  blk, 0, stream>>>(Wn2, wn2, 256, 64);

    // h0 = relu(x @ Wfc + bfc)   [f32 in, bf16 out]  128 rows/block
    gemm2<16, 128, false, true, true, true><<<dim3(N0c / 128), dim3(512), 0, stream>>>(
        x, nullptr, wfc, nullptr, bfc, h0);

    // ---- layer 0 ----
    build_and_aggregate(h0, src0, dst0, N1c, E0, hist, offs, bsum, ssrc, agg, stream);
    gemm2<16, 64, true, true, false, true><<<dim3(N1c / 128), dim3(512), 0, stream>>>(
        h0, agg, ws0, wn0, b0, h1);

    // ---- layer 1 ----
    build_and_aggregate(h1, src1, dst1, N2c, E1, hist, offs, bsum, ssrc, agg, stream);
    gemm2<16, 64, true, true, false, true><<<dim3(N2c / 128), dim3(512), 0, stream>>>(
        h1, agg, ws1, wn1, b1, h2);

    // ---- layer 2: out width 64, f32 out, no relu ----
    build_and_aggregate(h2, src2, dst2, N3c, E2, hist, offs, bsum, ssrc, agg, stream);
    gemm2<4, 256, true, false, false, false><<<dim3(N3c / 128), dim3(512), 0, stream>>>(
        h2, agg, ws2, wn2, b2, (float*)d_out);
}

// Round 10
// 937.811 us; speedup vs baseline: 1.2990x; 1.0498x over previous
//
#include <hip/hip_runtime.h>

// GraphSAGE: x(524288,256) -> FC relu -> 3x sage_conv -> out(8192,64)
// R10: batched CSR build (1 hist/scan/fill chain for all 3 layers, global
//      concat offsets + sentinel), 1 wconv kernel; 14 dispatches total.
//      K-phased B-in-LDS MFMA GEMMs + half-wave masked-batch gather agg (R9).
constexpr int N0c = 524288, N1c = 262144, N2c = 65536, N3c = 8192;
constexpr int NTOT = N1c + N2c + N3c;            // 335872 (= 328*1024)

typedef __attribute__((ext_vector_type(8))) short   bf16x8;
typedef __attribute__((ext_vector_type(4))) float   f32x4;
typedef __attribute__((ext_vector_type(8))) unsigned short u16x8;

__device__ inline unsigned short f2bf(float f) {
    union { float f; unsigned u; } v; v.f = f;
    unsigned r = v.u + 0x7FFF + ((v.u >> 16) & 1);   // RNE
    return (unsigned short)(r >> 16);
}
__device__ inline float bf2f(unsigned short u) {
    union { unsigned u; float f; } v; v.u = ((unsigned)u) << 16;
    return v.f;
}

__device__ inline void glds16(const void* g, void* l) {
    __builtin_amdgcn_global_load_lds(
        (const __attribute__((address_space(1))) unsigned int*)g,
        (__attribute__((address_space(3))) unsigned int*)l, 16, 0, 0);
}

// ---- all 7 weights -> bf16 transposed [N][K=256], one kernel ----
struct WPack { const float* w[7]; unsigned short* o[7]; };

__global__ __launch_bounds__(256)
void wconv_all(WPack p)
{
    const int idx = blockIdx.x * 256 + threadIdx.x;   // 0 .. 360447
    int widx, off, N;
    if (idx < 327680) { widx = idx >> 16; off = idx & 65535; N = 256; }
    else {
        const int r = idx - 327680;
        widx = 5 + (r >> 14); off = r & 16383; N = 64;
        if (widx > 6) return;
    }
    const int k = off / N, n = off % N;
    p.o[widx][n * 256 + k] = f2bf(p.w[widx][off]);
}

__device__ inline bf16x8 pack_bf8(const float* p) {
    const f32x4 u = *(const f32x4*)p;
    const f32x4 v = *(const f32x4*)(p + 4);
    bf16x8 t;
    #pragma unroll
    for (int j = 0; j < 4; ++j) {
        t[j]     = (short)f2bf(u[j]);
        t[j + 4] = (short)f2bf(v[j]);
    }
    return t;
}

// C[M x N] = act( A1 @ Wt1^T (+ A2 @ Wt2^T) + b ), K=256, N=NT*16.
// 512 thr = 8 waves, wave owns one 16-row strip (acc = NT*4 regs, persistent).
// Per phase: stage KC cols of W1 (and W2 if DUAL) into 64KB LDS via
// global_load_lds with pre-swizzled source; compute; barrier; restage.
template<int NT, int KC, bool DUAL, bool RELU, bool A_F32, bool OUT_BF16>
__global__ __launch_bounds__(512, 2)
void gemm2(const void* __restrict__ A1v, const void* __restrict__ A2v,
           const unsigned short* __restrict__ Wt1,
           const unsigned short* __restrict__ Wt2,
           const float* __restrict__ bias, void* __restrict__ Cv)
{
    constexpr int N     = NT * 16;
    constexpr int PH    = 256 / KC;
    constexpr int SLOTS = KC / 8;
    constexpr int GPM   = N * SLOTS;
    constexpr int TOTG  = GPM * (DUAL ? 2 : 1);
    static_assert(TOTG == 4096, "LDS sizing");
    __shared__ unsigned short Bs[TOTG * 8];

    const int t    = threadIdx.x;
    const int lane = t & 63;
    const int wv   = t >> 6;
    const int col  = lane & 15;
    const int kg   = lane >> 4;
    const int swz  = (col & 7) << 3;
    const long row0 = (long)blockIdx.x * 128 + wv * 16;

    const unsigned short* A1h = (const unsigned short*)A1v;
    const float*          A1f = (const float*)A1v;
    const unsigned short* A2h = (const unsigned short*)A2v;

    f32x4 acc[NT];
    #pragma unroll
    for (int nt = 0; nt < NT; ++nt) acc[nt] = (f32x4){0.f, 0.f, 0.f, 0.f};

    const long ar = (row0 + col) * 256;

    for (int kh = 0; kh < PH; ++kh) {
        if (kh) __syncthreads();
        #pragma unroll
        for (int it = 0; it < TOTG / 512; ++it) {
            const int g  = it * 512 + t;
            const int m  = DUAL ? (g / GPM) : 0;
            const int gm = DUAL ? (g % GPM) : g;
            const int n  = gm / SLOTS;
            const int s  = gm % SLOTS;
            const int ss = s ^ (n & 7);
            const unsigned short* srcb =
                (m ? Wt2 : Wt1) + n * 256 + kh * KC + ss * 8;
            glds16(srcb, &Bs[(it * 512 + wv * 64) * 8]);
        }
        __syncthreads();

        #pragma unroll
        for (int k0 = 0; k0 < KC; k0 += 32) {
            const int kx = (k0 + kg * 8) ^ swz;
            const long ac = ar + kh * KC + k0 + kg * 8;
            bf16x8 a1, a2;
            if constexpr (A_F32) a1 = pack_bf8(&A1f[ac]);
            else                 a1 = *(const bf16x8*)&A1h[ac];
            if constexpr (DUAL)  a2 = *(const bf16x8*)&A2h[ac];
            #pragma unroll
            for (int nt = 0; nt < NT; ++nt) {
                const bf16x8 b1 = *(const bf16x8*)&Bs[(nt * 16 + col) * KC + kx];
                acc[nt] = __builtin_amdgcn_mfma_f32_16x16x32_bf16(a1, b1, acc[nt], 0, 0, 0);
                if constexpr (DUAL) {
                    const bf16x8 b2 = *(const bf16x8*)&Bs[GPM * 8 + (nt * 16 + col) * KC + kx];
                    acc[nt] = __builtin_amdgcn_mfma_f32_16x16x32_bf16(a2, b2, acc[nt], 0, 0, 0);
                }
            }
        }
    }

    #pragma unroll
    for (int nt = 0; nt < NT; ++nt) {
        const int c = nt * 16 + col;
        const float bb = bias[c];
        #pragma unroll
        for (int rr = 0; rr < 4; ++rr) {
            const long row = row0 + kg * 4 + rr;
            float o = acc[nt][rr] + bb;
            if constexpr (RELU) o = fmaxf(o, 0.f);
            if constexpr (OUT_BF16)
                ((unsigned short*)Cv)[row * N + c] = f2bf(o);
            else
                ((float*)Cv)[row * N + c] = o;
        }
    }
}

// ---- batched CSR build over all 3 layers ----
struct CsrArgs {
    const int* src0; const int* dst0;
    const int* src1; const int* dst1;
    const int* src2; const int* dst2;
    int e0, e01, etot;        // E0, E0+E1, E0+E1+E2
};

__global__ __launch_bounds__(256)
void hist_all(CsrArgs a, int* __restrict__ hist)
{
    const int i = blockIdx.x * 256 + threadIdx.x;
    if (i >= a.etot) return;
    const int* dstp; int e, hb;
    if (i < a.e0)       { dstp = a.dst0; e = i;         hb = 0; }
    else if (i < a.e01) { dstp = a.dst1; e = i - a.e0;  hb = N1c; }
    else                { dstp = a.dst2; e = i - a.e01; hb = N1c + N2c; }
    atomicAdd(&hist[hb + dstp[e]], 1);
}

__global__ __launch_bounds__(256)
void scan1_k(const int* __restrict__ hist, int* __restrict__ offs,
             int* __restrict__ bsum, int n)
{
    __shared__ int sm[256];
    const int t = threadIdx.x;
    const int base = blockIdx.x * 1024 + t * 4;
    int4 v = make_int4(0, 0, 0, 0);
    if (base < n) v = *(const int4*)&hist[base];
    const int s = v.x + v.y + v.z + v.w;
    int val = s;
    sm[t] = val; __syncthreads();
    #pragma unroll
    for (int off = 1; off < 256; off <<= 1) {
        const int add = (t >= off) ? sm[t - off] : 0;
        __syncthreads();
        val += add;
        sm[t] = val;
        __syncthreads();
    }
    const int excl = val - s;
    if (base < n) {
        offs[base]     = excl;
        offs[base + 1] = excl + v.x;
        offs[base + 2] = excl + v.x + v.y;
        offs[base + 3] = excl + v.x + v.y + v.z;
    }
    if (t == 255) bsum[blockIdx.x] = val;
}

// one block of 512: exclusive scan of block totals (nb <= 512)
__global__ __launch_bounds__(512)
void scan2_k(int* __restrict__ bsum, int nb)
{
    __shared__ int sm[512];
    const int t = threadIdx.x;
    const int s = (t < nb) ? bsum[t] : 0;
    int val = s;
    sm[t] = val; __syncthreads();
    #pragma unroll
    for (int off = 1; off < 512; off <<= 1) {
        const int add = (t >= off) ? sm[t - off] : 0;
        __syncthreads();
        val += add;
        sm[t] = val;
        __syncthreads();
    }
    if (t < nb) bsum[t] = val - s;
}

__global__ __launch_bounds__(256)
void scan3_k(int* __restrict__ offs, const int* __restrict__ bsum, int etot)
{
    const int i = blockIdx.x * 256 + threadIdx.x;
    offs[i] += bsum[i >> 10];
    if (i == 0) offs[NTOT] = etot;               // sentinel
}

__global__ __launch_bounds__(256)
void fill_all(CsrArgs a, const int* __restrict__ offs, int* __restrict__ hist,
              int* __restrict__ ssrc)
{
    const int i = blockIdx.x * 256 + threadIdx.x;
    if (i >= a.etot) return;
    const int* dstp; const int* srcp; int e, hb;
    if (i < a.e0)       { dstp = a.dst0; srcp = a.src0; e = i;         hb = 0; }
    else if (i < a.e01) { dstp = a.dst1; srcp = a.src1; e = i - a.e0;  hb = N1c; }
    else                { dstp = a.dst2; srcp = a.src2; e = i - a.e01; hb = N1c + N2c; }
    const int g = hb + dstp[e];
    const int p = atomicAdd(&hist[g], -1) - 1;
    ssrc[offs[g] + p] = srcp[e];
}

// one wave per dst row. Half-wave (32 lanes) covers a 512B row via u16x8;
// the two halves process edge pairs. Masked 16-edge batches keep 8 gathers
// in flight with NO serial tail. ob = offs + layer_base (sentinel-terminated).
__global__ __launch_bounds__(256)
void agg_k(const unsigned short* __restrict__ h, const int* __restrict__ ssrc,
           const int* __restrict__ ob, unsigned short* __restrict__ agg, int n)
{
    const int w    = blockIdx.x * 4 + (threadIdx.x >> 6);
    const int lane = threadIdx.x & 63;
    if (w >= n) return;
    const int beg = ob[w];
    const int end = ob[w + 1];
    const int hf  = lane >> 5;
    const int co  = (lane & 31) * 8;

    float acc[8] = {0.f, 0.f, 0.f, 0.f, 0.f, 0.f, 0.f, 0.f};

    for (int j = beg; j < end; j += 16) {
        u16x8 v[8];
        bool  ok[8];
        #pragma unroll
        for (int q = 0; q < 8; ++q) {
            const int e  = j + 2 * q + hf;
            ok[q] = (e < end);
            const int es = ok[q] ? e : (end - 1);
            v[q] = *(const u16x8*)&h[(size_t)ssrc[es] * 256 + co];
        }
        #pragma unroll
        for (int q = 0; q < 8; ++q)
            #pragma unroll
            for (int c = 0; c < 8; ++c)
                acc[c] += ok[q] ? bf2f(v[q][c]) : 0.0f;
    }

    #pragma unroll
    for (int c = 0; c < 8; ++c) acc[c] += __shfl_xor(acc[c], 32);

    if (hf == 0) {
        const float inv = 1.0f / fmaxf((float)(end - beg), 1.0f);
        u16x8 o;
        #pragma unroll
        for (int c = 0; c < 8; ++c) o[c] = f2bf(acc[c] * inv);
        *(u16x8*)&agg[(size_t)w * 256 + co] = o;
    }
}

extern "C" void kernel_launch(void* const* d_in, const int* in_sizes, int n_in,
                              void* d_out, int out_size, void* d_ws, size_t ws_size,
                              hipStream_t stream)
{
    const float* x    = (const float*)d_in[0];
    const int*   src0 = (const int*)d_in[1];
    const int*   dst0 = (const int*)d_in[2];
    const int*   src1 = (const int*)d_in[3];
    const int*   dst1 = (const int*)d_in[4];
    const int*   src2 = (const int*)d_in[5];
    const int*   dst2 = (const int*)d_in[6];
    const float* Wfc  = (const float*)d_in[10];
    const float* bfc  = (const float*)d_in[11];
    const float* Ws0  = (const float*)d_in[12];
    const float* Wn0  = (const float*)d_in[13];
    const float* b0   = (const float*)d_in[14];
    const float* Ws1  = (const float*)d_in[15];
    const float* Wn1  = (const float*)d_in[16];
    const float* b1   = (const float*)d_in[17];
    const float* Ws2  = (const float*)d_in[18];
    const float* Wn2  = (const float*)d_in[19];
    const float* b2   = (const float*)d_in[20];
    const int E0 = in_sizes[1], E1 = in_sizes[3], E2 = in_sizes[5];
    const int Etot = E0 + E1 + E2;

    char* ws = (char*)d_ws;
    unsigned short* h0   = (unsigned short*)ws;                    // 256 MiB
    unsigned short* h1   = (unsigned short*)(ws + (256ULL << 20)); // 128 MiB
    unsigned short* h2   = (unsigned short*)(ws + (384ULL << 20)); //  32 MiB
    unsigned short* agg  = (unsigned short*)(ws + (416ULL << 20)); // 128 MiB
    unsigned short* Wt   = (unsigned short*)(ws + (544ULL << 20)); //   1 MiB
    int*            hist = (int*)(ws + (545ULL << 20));            // 1.31 MiB
    int*            offs = (int*)(ws + (547ULL << 20));            // 1.31 MiB +1
    int*            bsum = (int*)(ws + (549ULL << 20));            //   2 KiB
    int*            ssrc = (int*)(ws + (550ULL << 20));            // 12.9 MiB

    unsigned short* wfc = Wt;
    unsigned short* ws0 = Wt + 65536;
    unsigned short* wn0 = Wt + 131072;
    unsigned short* ws1 = Wt + 196608;
    unsigned short* wn1 = Wt + 262144;
    unsigned short* ws2 = Wt + 327680;
    unsigned short* wn2 = Wt + 344064;

    const dim3 blk(256);

    // 1) weights -> bf16 transposed [N][K]
    WPack wp;
    wp.w[0] = Wfc; wp.w[1] = Ws0; wp.w[2] = Wn0; wp.w[3] = Ws1; wp.w[4] = Wn1;
    wp.w[5] = Ws2; wp.w[6] = Wn2;
    wp.o[0] = wfc; wp.o[1] = ws0; wp.o[2] = wn0; wp.o[3] = ws1; wp.o[4] = wn1;
    wp.o[5] = ws2; wp.o[6] = wn2;
    wconv_all<<<dim3(1408), blk, 0, stream>>>(wp);

    // 2) batched CSR build (all 3 layers, before the MLP chain)
    CsrArgs ca;
    ca.src0 = src0; ca.dst0 = dst0; ca.src1 = src1; ca.dst1 = dst1;
    ca.src2 = src2; ca.dst2 = dst2;
    ca.e0 = E0; ca.e01 = E0 + E1; ca.etot = Etot;
    hipMemsetAsync(hist, 0, (size_t)NTOT * 4, stream);
    hist_all<<<dim3((Etot + 255) / 256), blk, 0, stream>>>(ca, hist);
    scan1_k<<<dim3(NTOT / 1024), blk, 0, stream>>>(hist, offs, bsum, NTOT);
    scan2_k<<<dim3(1), dim3(512), 0, stream>>>(bsum, NTOT / 1024);
    scan3_k<<<dim3(NTOT / 256), blk, 0, stream>>>(offs, bsum, Etot);
    fill_all<<<dim3((Etot + 255) / 256), blk, 0, stream>>>(ca, offs, hist, ssrc);

    // 3) h0 = relu(x @ Wfc + bfc)   [f32 in, bf16 out]  128 rows/block
    gemm2<16, 128, false, true, true, true><<<dim3(N0c / 128), dim3(512), 0, stream>>>(
        x, nullptr, wfc, nullptr, bfc, h0);

    // 4) layer 0
    agg_k<<<dim3(N1c / 4), blk, 0, stream>>>(h0, ssrc, offs, agg, N1c);
    gemm2<16, 64, true, true, false, true><<<dim3(N1c / 128), dim3(512), 0, stream>>>(
        h0, agg, ws0, wn0, b0, h1);

    // 5) layer 1
    agg_k<<<dim3(N2c / 4), blk, 0, stream>>>(h1, ssrc, offs + N1c, agg, N2c);
    gemm2<16, 64, true, true, false, true><<<dim3(N2c / 128), dim3(512), 0, stream>>>(
        h1, agg, ws1, wn1, b1, h2);

    // 6) layer 2: out width 64, f32 out, no relu
    agg_k<<<dim3(N3c / 4), blk, 0, stream>>>(h2, ssrc, offs + N1c + N2c, agg, N3c);
    gemm2<4, 256, true, false, false, false><<<dim3(N3c / 128), dim3(512), 0, stream>>>(
        h2, agg, ws2, wn2, b2, (float*)d_out);
}

// Round 12
// 850.701 us; speedup vs baseline: 1.4320x; 1.1024x over previous
//
#include <hip/hip_runtime.h>

// GraphSAGE: x(524288,256) -> FC relu -> 3x sage_conv -> out(8192,64)
// R11: single-atomic CSR (rank/place), hist-zero fused into wconv, agg exact
//      batches + small-tail. K-phased B-in-LDS MFMA GEMMs (R7), bf16 acts.
constexpr int N0c = 524288, N1c = 262144, N2c = 65536, N3c = 8192;
constexpr int NTOT = N1c + N2c + N3c;            // 335872 (= 328*1024)

typedef __attribute__((ext_vector_type(8))) short   bf16x8;
typedef __attribute__((ext_vector_type(4))) float   f32x4;
typedef __attribute__((ext_vector_type(8))) unsigned short u16x8;

__device__ inline unsigned short f2bf(float f) {
    union { float f; unsigned u; } v; v.f = f;
    unsigned r = v.u + 0x7FFF + ((v.u >> 16) & 1);   // RNE
    return (unsigned short)(r >> 16);
}
__device__ inline float bf2f(unsigned short u) {
    union { unsigned u; float f; } v; v.u = ((unsigned)u) << 16;
    return v.f;
}

__device__ inline void glds16(const void* g, void* l) {
    __builtin_amdgcn_global_load_lds(
        (const __attribute__((address_space(1))) unsigned int*)g,
        (__attribute__((address_space(3))) unsigned int*)l, 16, 0, 0);
}

// ---- weights -> bf16 transposed [N][K=256] + zero hist, one kernel ----
struct WPack { const float* w[7]; unsigned short* o[7]; };

__global__ __launch_bounds__(256)
void wconv_all(WPack p, int* __restrict__ hist)
{
    if (blockIdx.x >= 1408) {                       // zero hist: 328 blocks
        const int zid = (blockIdx.x - 1408) * 256 + threadIdx.x;
        ((int4*)hist)[zid] = make_int4(0, 0, 0, 0);
        return;
    }
    const int idx = blockIdx.x * 256 + threadIdx.x;   // 0 .. 360447
    int widx, off, N;
    if (idx < 327680) { widx = idx >> 16; off = idx & 65535; N = 256; }
    else {
        const int r = idx - 327680;
        widx = 5 + (r >> 14); off = r & 16383; N = 64;
        if (widx > 6) return;
    }
    const int k = off / N, n = off % N;
    p.o[widx][n * 256 + k] = f2bf(p.w[widx][off]);
}

__device__ inline bf16x8 pack_bf8(const float* p) {
    const f32x4 u = *(const f32x4*)p;
    const f32x4 v = *(const f32x4*)(p + 4);
    bf16x8 t;
    #pragma unroll
    for (int j = 0; j < 4; ++j) {
        t[j]     = (short)f2bf(u[j]);
        t[j + 4] = (short)f2bf(v[j]);
    }
    return t;
}

// C[M x N] = act( A1 @ Wt1^T (+ A2 @ Wt2^T) + b ), K=256, N=NT*16.
template<int NT, int KC, bool DUAL, bool RELU, bool A_F32, bool OUT_BF16>
__global__ __launch_bounds__(512, 2)
void gemm2(const void* __restrict__ A1v, const void* __restrict__ A2v,
           const unsigned short* __restrict__ Wt1,
           const unsigned short* __restrict__ Wt2,
           const float* __restrict__ bias, void* __restrict__ Cv)
{
    constexpr int N     = NT * 16;
    constexpr int PH    = 256 / KC;
    constexpr int SLOTS = KC / 8;
    constexpr int GPM   = N * SLOTS;
    constexpr int TOTG  = GPM * (DUAL ? 2 : 1);
    static_assert(TOTG == 4096, "LDS sizing");
    __shared__ unsigned short Bs[TOTG * 8];

    const int t    = threadIdx.x;
    const int lane = t & 63;
    const int wv   = t >> 6;
    const int col  = lane & 15;
    const int kg   = lane >> 4;
    const int swz  = (col & 7) << 3;
    const long row0 = (long)blockIdx.x * 128 + wv * 16;

    const unsigned short* A1h = (const unsigned short*)A1v;
    const float*          A1f = (const float*)A1v;
    const unsigned short* A2h = (const unsigned short*)A2v;

    f32x4 acc[NT];
    #pragma unroll
    for (int nt = 0; nt < NT; ++nt) acc[nt] = (f32x4){0.f, 0.f, 0.f, 0.f};

    const long ar = (row0 + col) * 256;

    for (int kh = 0; kh < PH; ++kh) {
        if (kh) __syncthreads();
        #pragma unroll
        for (int it = 0; it < TOTG / 512; ++it) {
            const int g  = it * 512 + t;
            const int m  = DUAL ? (g / GPM) : 0;
            const int gm = DUAL ? (g % GPM) : g;
            const int n  = gm / SLOTS;
            const int s  = gm % SLOTS;
            const int ss = s ^ (n & 7);
            const unsigned short* srcb =
                (m ? Wt2 : Wt1) + n * 256 + kh * KC + ss * 8;
            glds16(srcb, &Bs[(it * 512 + wv * 64) * 8]);
        }
        __syncthreads();

        #pragma unroll
        for (int k0 = 0; k0 < KC; k0 += 32) {
            const int kx = (k0 + kg * 8) ^ swz;
            const long ac = ar + kh * KC + k0 + kg * 8;
            bf16x8 a1, a2;
            if constexpr (A_F32) a1 = pack_bf8(&A1f[ac]);
            else                 a1 = *(const bf16x8*)&A1h[ac];
            if constexpr (DUAL)  a2 = *(const bf16x8*)&A2h[ac];
            #pragma unroll
            for (int nt = 0; nt < NT; ++nt) {
                const bf16x8 b1 = *(const bf16x8*)&Bs[(nt * 16 + col) * KC + kx];
                acc[nt] = __builtin_amdgcn_mfma_f32_16x16x32_bf16(a1, b1, acc[nt], 0, 0, 0);
                if constexpr (DUAL) {
                    const bf16x8 b2 = *(const bf16x8*)&Bs[GPM * 8 + (nt * 16 + col) * KC + kx];
                    acc[nt] = __builtin_amdgcn_mfma_f32_16x16x32_bf16(a2, b2, acc[nt], 0, 0, 0);
                }
            }
        }
    }

    #pragma unroll
    for (int nt = 0; nt < NT; ++nt) {
        const int c = nt * 16 + col;
        const float bb = bias[c];
        #pragma unroll
        for (int rr = 0; rr < 4; ++rr) {
            const long row = row0 + kg * 4 + rr;
            float o = acc[nt][rr] + bb;
            if constexpr (RELU) o = fmaxf(o, 0.f);
            if constexpr (OUT_BF16)
                ((unsigned short*)Cv)[row * N + c] = f2bf(o);
            else
                ((float*)Cv)[row * N + c] = o;
        }
    }
}

// ---- batched CSR build over all 3 layers (single atomic pass) ----
struct CsrArgs {
    const int* src0; const int* dst0;
    const int* src1; const int* dst1;
    const int* src2; const int* dst2;
    int e0, e01, etot;
};

// one atomic pass: builds hist AND per-edge rank within its dst segment
__global__ __launch_bounds__(256)
void rank_k(CsrArgs a, int* __restrict__ hist, int* __restrict__ rank)
{
    const int i = blockIdx.x * 256 + threadIdx.x;
    if (i >= a.etot) return;
    const int* dstp; int e, hb;
    if (i < a.e0)       { dstp = a.dst0; e = i;         hb = 0; }
    else if (i < a.e01) { dstp = a.dst1; e = i - a.e0;  hb = N1c; }
    else                { dstp = a.dst2; e = i - a.e01; hb = N1c + N2c; }
    rank[i] = atomicAdd(&hist[hb + dstp[e]], 1);
}

__global__ __launch_bounds__(256)
void scan1_k(const int* __restrict__ hist, int* __restrict__ offs,
             int* __restrict__ bsum, int n)
{
    __shared__ int sm[256];
    const int t = threadIdx.x;
    const int base = blockIdx.x * 1024 + t * 4;
    int4 v = make_int4(0, 0, 0, 0);
    if (base < n) v = *(const int4*)&hist[base];
    const int s = v.x + v.y + v.z + v.w;
    int val = s;
    sm[t] = val; __syncthreads();
    #pragma unroll
    for (int off = 1; off < 256; off <<= 1) {
        const int add = (t >= off) ? sm[t - off] : 0;
        __syncthreads();
        val += add;
        sm[t] = val;
        __syncthreads();
    }
    const int excl = val - s;
    if (base < n) {
        offs[base]     = excl;
        offs[base + 1] = excl + v.x;
        offs[base + 2] = excl + v.x + v.y;
        offs[base + 3] = excl + v.x + v.y + v.z;
    }
    if (t == 255) bsum[blockIdx.x] = val;
}

__global__ __launch_bounds__(512)
void scan2_k(int* __restrict__ bsum, int nb)
{
    __shared__ int sm[512];
    const int t = threadIdx.x;
    const int s = (t < nb) ? bsum[t] : 0;
    int val = s;
    sm[t] = val; __syncthreads();
    #pragma unroll
    for (int off = 1; off < 512; off <<= 1) {
        const int add = (t >= off) ? sm[t - off] : 0;
        __syncthreads();
        val += add;
        sm[t] = val;
        __syncthreads();
    }
    if (t < nb) bsum[t] = val - s;
}

__global__ __launch_bounds__(256)
void scan3_k(int* __restrict__ offs, const int* __restrict__ bsum, int etot)
{
    const int i = blockIdx.x * 256 + threadIdx.x;
    offs[i] += bsum[i >> 10];
    if (i == 0) offs[NTOT] = etot;               // sentinel
}

// atomic-free placement using precomputed rank
__global__ __launch_bounds__(256)
void place_k(CsrArgs a, const int* __restrict__ offs, const int* __restrict__ rank,
             int* __restrict__ ssrc)
{
    const int i = blockIdx.x * 256 + threadIdx.x;
    if (i >= a.etot) return;
    const int* dstp; const int* srcp; int e, hb;
    if (i < a.e0)       { dstp = a.dst0; srcp = a.src0; e = i;         hb = 0; }
    else if (i < a.e01) { dstp = a.dst1; srcp = a.src1; e = i - a.e0;  hb = N1c; }
    else                { dstp = a.dst2; srcp = a.src2; e = i - a.e01; hb = N1c + N2c; }
    const int g = hb + dstp[e];
    ssrc[offs[g] + rank[i]] = srcp[e];
}

// one wave per dst row; half-wave covers a 512B row via u16x8.
// Exact 16-edge batches (no mask), then one masked 8- or 4-load tail batch.
__global__ __launch_bounds__(256)
void agg_k(const unsigned short* __restrict__ h, const int* __restrict__ ssrc,
           const int* __restrict__ ob, unsigned short* __restrict__ agg, int n)
{
    const int w    = blockIdx.x * 4 + (threadIdx.x >> 6);
    const int lane = threadIdx.x & 63;
    if (w >= n) return;
    const int beg = ob[w];
    const int end = ob[w + 1];
    const int hf  = lane >> 5;
    const int co  = (lane & 31) * 8;

    float acc[8] = {0.f, 0.f, 0.f, 0.f, 0.f, 0.f, 0.f, 0.f};

    int j = beg;
    for (; j + 16 <= end; j += 16) {             // exact batches: no masking
        u16x8 v[8];
        #pragma unroll
        for (int q = 0; q < 8; ++q)
            v[q] = *(const u16x8*)&h[(size_t)ssrc[j + 2 * q + hf] * 256 + co];
        #pragma unroll
        for (int q = 0; q < 8; ++q)
            #pragma unroll
            for (int c = 0; c < 8; ++c) acc[c] += bf2f(v[q][c]);
    }
    const int rem = end - j;
    if (rem > 8) {                               // masked 8-load batch
        u16x8 v[8]; bool ok[8];
        #pragma unroll
        for (int q = 0; q < 8; ++q) {
            const int e = j + 2 * q + hf;
            ok[q] = (e < end);
            v[q] = *(const u16x8*)&h[(size_t)ssrc[ok[q] ? e : (end - 1)] * 256 + co];
        }
        #pragma unroll
        for (int q = 0; q < 8; ++q)
            #pragma unroll
            for (int c = 0; c < 8; ++c) acc[c] += ok[q] ? bf2f(v[q][c]) : 0.0f;
    } else if (rem > 0) {                        // masked 4-load batch
        u16x8 v[4]; bool ok[4];
        #pragma unroll
        for (int q = 0; q < 4; ++q) {
            const int e = j + 2 * q + hf;
            ok[q] = (e < end);
            v[q] = *(const u16x8*)&h[(size_t)ssrc[ok[q] ? e : (end - 1)] * 256 + co];
        }
        #pragma unroll
        for (int q = 0; q < 4; ++q)
            #pragma unroll
            for (int c = 0; c < 8; ++c) acc[c] += ok[q] ? bf2f(v[q][c]) : 0.0f;
    }

    #pragma unroll
    for (int c = 0; c < 8; ++c) acc[c] += __shfl_xor(acc[c], 32);

    if (hf == 0) {
        const float inv = 1.0f / fmaxf((float)(end - beg), 1.0f);
        u16x8 o;
        #pragma unroll
        for (int c = 0; c < 8; ++c) o[c] = f2bf(acc[c] * inv);
        *(u16x8*)&agg[(size_t)w * 256 + co] = o;
    }
}

extern "C" void kernel_launch(void* const* d_in, const int* in_sizes, int n_in,
                              void* d_out, int out_size, void* d_ws, size_t ws_size,
                              hipStream_t stream)
{
    const float* x    = (const float*)d_in[0];
    const int*   src0 = (const int*)d_in[1];
    const int*   dst0 = (const int*)d_in[2];
    const int*   src1 = (const int*)d_in[3];
    const int*   dst1 = (const int*)d_in[4];
    const int*   src2 = (const int*)d_in[5];
    const int*   dst2 = (const int*)d_in[6];
    const float* Wfc  = (const float*)d_in[10];
    const float* bfc  = (const float*)d_in[11];
    const float* Ws0  = (const float*)d_in[12];
    const float* Wn0  = (const float*)d_in[13];
    const float* b0   = (const float*)d_in[14];
    const float* Ws1  = (const float*)d_in[15];
    const float* Wn1  = (const float*)d_in[16];
    const float* b1   = (const float*)d_in[17];
    const float* Ws2  = (const float*)d_in[18];
    const float* Wn2  = (const float*)d_in[19];
    const float* b2   = (const float*)d_in[20];
    const int E0 = in_sizes[1], E1 = in_sizes[3], E2 = in_sizes[5];
    const int Etot = E0 + E1 + E2;

    char* ws = (char*)d_ws;
    unsigned short* h0   = (unsigned short*)ws;                    // 256 MiB
    unsigned short* h1   = (unsigned short*)(ws + (256ULL << 20)); // 128 MiB
    unsigned short* h2   = (unsigned short*)(ws + (384ULL << 20)); //  32 MiB
    unsigned short* agg  = (unsigned short*)(ws + (416ULL << 20)); // 128 MiB
    unsigned short* Wt   = (unsigned short*)(ws + (544ULL << 20)); //   1 MiB
    int*            hist = (int*)(ws + (545ULL << 20));            // 1.31 MiB
    int*            offs = (int*)(ws + (547ULL << 20));            // 1.31 MiB +1
    int*            bsum = (int*)(ws + (549ULL << 20));            //   2 KiB
    int*            ssrc = (int*)(ws + (550ULL << 20));            // 12.9 MiB
    int*            rank = (int*)(ws + (564ULL << 20));            // 12.9 MiB

    unsigned short* wfc = Wt;
    unsigned short* ws0 = Wt + 65536;
    unsigned short* wn0 = Wt + 131072;
    unsigned short* ws1 = Wt + 196608;
    unsigned short* wn1 = Wt + 262144;
    unsigned short* ws2 = Wt + 327680;
    unsigned short* wn2 = Wt + 344064;

    const dim3 blk(256);

    // 1) weights -> bf16 [N][K] + zero hist (fused)
    WPack wp;
    wp.w[0] = Wfc; wp.w[1] = Ws0; wp.w[2] = Wn0; wp.w[3] = Ws1; wp.w[4] = Wn1;
    wp.w[5] = Ws2; wp.w[6] = Wn2;
    wp.o[0] = wfc; wp.o[1] = ws0; wp.o[2] = wn0; wp.o[3] = ws1; wp.o[4] = wn1;
    wp.o[5] = ws2; wp.o[6] = wn2;
    wconv_all<<<dim3(1408 + 328), blk, 0, stream>>>(wp, hist);

    // 2) batched CSR build (single atomic pass)
    CsrArgs ca;
    ca.src0 = src0; ca.dst0 = dst0; ca.src1 = src1; ca.dst1 = dst1;
    ca.src2 = src2; ca.dst2 = dst2;
    ca.e0 = E0; ca.e01 = E0 + E1; ca.etot = Etot;
    rank_k<<<dim3((Etot + 255) / 256), blk, 0, stream>>>(ca, hist, rank);
    scan1_k<<<dim3(NTOT / 1024), blk, 0, stream>>>(hist, offs, bsum, NTOT);
    scan2_k<<<dim3(1), dim3(512), 0, stream>>>(bsum, NTOT / 1024);
    scan3_k<<<dim3(NTOT / 256), blk, 0, stream>>>(offs, bsum, Etot);
    place_k<<<dim3((Etot + 255) / 256), blk, 0, stream>>>(ca, offs, rank, ssrc);

    // 3) h0 = relu(x @ Wfc + bfc)
    gemm2<16, 128, false, true, true, true><<<dim3(N0c / 128), dim3(512), 0, stream>>>(
        x, nullptr, wfc, nullptr, bfc, h0);

    // 4) layer 0
    agg_k<<<dim3(N1c / 4), blk, 0, stream>>>(h0, ssrc, offs, agg, N1c);
    gemm2<16, 64, true, true, false, true><<<dim3(N1c / 128), dim3(512), 0, stream>>>(
        h0, agg, ws0, wn0, b0, h1);

    // 5) layer 1
    agg_k<<<dim3(N2c / 4), blk, 0, stream>>>(h1, ssrc, offs + N1c, agg, N2c);
    gemm2<16, 64, true, true, false, true><<<dim3(N2c / 128), dim3(512), 0, stream>>>(
        h1, agg, ws1, wn1, b1, h2);

    // 6) layer 2
    agg_k<<<dim3(N3c / 4), blk, 0, stream>>>(h2, ssrc, offs + N1c + N2c, agg, N3c);
    gemm2<4, 256, true, false, false, false><<<dim3(N3c / 128), dim3(512), 0, stream>>>(
        h2, agg, ws2, wn2, b2, (float*)d_out);
}

// Round 13
// 847.048 us; speedup vs baseline: 1.4382x; 1.0043x over previous
//
#include <hip/hip_runtime.h>

// GraphSAGE: x(524288,256) -> FC relu -> 3x sage_conv -> out(8192,64)
// R13: rank_k fused into the FC GEMM dispatch (overlaps CSR atomic pass under
//      the HBM-bound FC). Otherwise identical to R11/R12.
constexpr int N0c = 524288, N1c = 262144, N2c = 65536, N3c = 8192;
constexpr int NTOT = N1c + N2c + N3c;            // 335872 (= 328*1024)

typedef __attribute__((ext_vector_type(8))) short   bf16x8;
typedef __attribute__((ext_vector_type(4))) float   f32x4;
typedef __attribute__((ext_vector_type(8))) unsigned short u16x8;

__device__ inline unsigned short f2bf(float f) {
    union { float f; unsigned u; } v; v.f = f;
    unsigned r = v.u + 0x7FFF + ((v.u >> 16) & 1);   // RNE
    return (unsigned short)(r >> 16);
}
__device__ inline float bf2f(unsigned short u) {
    union { unsigned u; float f; } v; v.u = ((unsigned)u) << 16;
    return v.f;
}

__device__ inline void glds16(const void* g, void* l) {
    __builtin_amdgcn_global_load_lds(
        (const __attribute__((address_space(1))) unsigned int*)g,
        (__attribute__((address_space(3))) unsigned int*)l, 16, 0, 0);
}

// ---- weights -> bf16 transposed [N][K=256] + zero hist, one kernel ----
struct WPack { const float* w[7]; unsigned short* o[7]; };

__global__ __launch_bounds__(256)
void wconv_all(WPack p, int* __restrict__ hist)
{
    if (blockIdx.x >= 1408) {                       // zero hist: 328 blocks
        const int zid = (blockIdx.x - 1408) * 256 + threadIdx.x;
        ((int4*)hist)[zid] = make_int4(0, 0, 0, 0);
        return;
    }
    const int idx = blockIdx.x * 256 + threadIdx.x;   // 0 .. 360447
    int widx, off, N;
    if (idx < 327680) { widx = idx >> 16; off = idx & 65535; N = 256; }
    else {
        const int r = idx - 327680;
        widx = 5 + (r >> 14); off = r & 16383; N = 64;
        if (widx > 6) return;
    }
    const int k = off / N, n = off % N;
    p.o[widx][n * 256 + k] = f2bf(p.w[widx][off]);
}

__device__ inline bf16x8 pack_bf8(const float* p) {
    const f32x4 u = *(const f32x4*)p;
    const f32x4 v = *(const f32x4*)(p + 4);
    bf16x8 t;
    #pragma unroll
    for (int j = 0; j < 4; ++j) {
        t[j]     = (short)f2bf(u[j]);
        t[j + 4] = (short)f2bf(v[j]);
    }
    return t;
}

struct CsrArgs {
    const int* src0; const int* dst0;
    const int* src1; const int* dst1;
    const int* src2; const int* dst2;
    int e0, e01, etot;
};

// ---- fused: FC GEMM (blocks < gemmBlocks) + rank pass (blocks >= gemmBlocks) ----
// FC: C[M x 256] = relu( A(f32) @ Wt^T + b ), KC=128, 2 phases, 512 thr/8 waves.
__global__ __launch_bounds__(512, 2)
void fc_rank_k(const float* __restrict__ A1f, const unsigned short* __restrict__ Wt1,
               const float* __restrict__ bias, unsigned short* __restrict__ Cv,
               CsrArgs a, int* __restrict__ hist, int* __restrict__ rank,
               int gemmBlocks)
{
    if ((int)blockIdx.x >= gemmBlocks) {
        // ---- rank: one atomic pass builds hist + per-edge rank ----
        const int i = ((int)blockIdx.x - gemmBlocks) * 512 + (int)threadIdx.x;
        if (i >= a.etot) return;
        const int* dstp; int e, hb;
        if (i < a.e0)       { dstp = a.dst0; e = i;         hb = 0; }
        else if (i < a.e01) { dstp = a.dst1; e = i - a.e0;  hb = N1c; }
        else                { dstp = a.dst2; e = i - a.e01; hb = N1c + N2c; }
        rank[i] = atomicAdd(&hist[hb + dstp[e]], 1);
        return;
    }

    constexpr int KC = 128, SLOTS = KC / 8, GPM = 256 * SLOTS;   // 4096 granules
    __shared__ unsigned short Bs[GPM * 8];

    const int t    = threadIdx.x;
    const int lane = t & 63;
    const int wv   = t >> 6;
    const int col  = lane & 15;
    const int kg   = lane >> 4;
    const int swz  = (col & 7) << 3;
    const long row0 = (long)blockIdx.x * 128 + wv * 16;

    f32x4 acc[16];
    #pragma unroll
    for (int nt = 0; nt < 16; ++nt) acc[nt] = (f32x4){0.f, 0.f, 0.f, 0.f};

    const long ar = (row0 + col) * 256;

    for (int kh = 0; kh < 2; ++kh) {
        if (kh) __syncthreads();
        #pragma unroll
        for (int it = 0; it < GPM / 512; ++it) {
            const int g  = it * 512 + t;
            const int n  = g / SLOTS;
            const int s  = g % SLOTS;
            const int ss = s ^ (n & 7);
            glds16(Wt1 + n * 256 + kh * KC + ss * 8, &Bs[(it * 512 + wv * 64) * 8]);
        }
        __syncthreads();

        #pragma unroll
        for (int k0 = 0; k0 < KC; k0 += 32) {
            const int kx = (k0 + kg * 8) ^ swz;
            const bf16x8 a1 = pack_bf8(&A1f[ar + kh * KC + k0 + kg * 8]);
            #pragma unroll
            for (int nt = 0; nt < 16; ++nt) {
                const bf16x8 b1 = *(const bf16x8*)&Bs[(nt * 16 + col) * KC + kx];
                acc[nt] = __builtin_amdgcn_mfma_f32_16x16x32_bf16(a1, b1, acc[nt], 0, 0, 0);
            }
        }
    }

    #pragma unroll
    for (int nt = 0; nt < 16; ++nt) {
        const int c = nt * 16 + col;
        const float bb = bias[c];
        #pragma unroll
        for (int rr = 0; rr < 4; ++rr) {
            const long row = row0 + kg * 4 + rr;
            Cv[row * 256 + c] = f2bf(fmaxf(acc[nt][rr] + bb, 0.f));
        }
    }
}

// C[M x N] = act( A1 @ Wt1^T (+ A2 @ Wt2^T) + b ), K=256, N=NT*16.
template<int NT, int KC, bool DUAL, bool RELU, bool A_F32, bool OUT_BF16>
__global__ __launch_bounds__(512, 2)
void gemm2(const void* __restrict__ A1v, const void* __restrict__ A2v,
           const unsigned short* __restrict__ Wt1,
           const unsigned short* __restrict__ Wt2,
           const float* __restrict__ bias, void* __restrict__ Cv)
{
    constexpr int N     = NT * 16;
    constexpr int PH    = 256 / KC;
    constexpr int SLOTS = KC / 8;
    constexpr int GPM   = N * SLOTS;
    constexpr int TOTG  = GPM * (DUAL ? 2 : 1);
    static_assert(TOTG == 4096, "LDS sizing");
    __shared__ unsigned short Bs[TOTG * 8];

    const int t    = threadIdx.x;
    const int lane = t & 63;
    const int wv   = t >> 6;
    const int col  = lane & 15;
    const int kg   = lane >> 4;
    const int swz  = (col & 7) << 3;
    const long row0 = (long)blockIdx.x * 128 + wv * 16;

    const unsigned short* A1h = (const unsigned short*)A1v;
    const float*          A1f = (const float*)A1v;
    const unsigned short* A2h = (const unsigned short*)A2v;

    f32x4 acc[NT];
    #pragma unroll
    for (int nt = 0; nt < NT; ++nt) acc[nt] = (f32x4){0.f, 0.f, 0.f, 0.f};

    const long ar = (row0 + col) * 256;

    for (int kh = 0; kh < PH; ++kh) {
        if (kh) __syncthreads();
        #pragma unroll
        for (int it = 0; it < TOTG / 512; ++it) {
            const int g  = it * 512 + t;
            const int m  = DUAL ? (g / GPM) : 0;
            const int gm = DUAL ? (g % GPM) : g;
            const int n  = gm / SLOTS;
            const int s  = gm % SLOTS;
            const int ss = s ^ (n & 7);
            const unsigned short* srcb =
                (m ? Wt2 : Wt1) + n * 256 + kh * KC + ss * 8;
            glds16(srcb, &Bs[(it * 512 + wv * 64) * 8]);
        }
        __syncthreads();

        #pragma unroll
        for (int k0 = 0; k0 < KC; k0 += 32) {
            const int kx = (k0 + kg * 8) ^ swz;
            const long ac = ar + kh * KC + k0 + kg * 8;
            bf16x8 a1, a2;
            if constexpr (A_F32) a1 = pack_bf8(&A1f[ac]);
            else                 a1 = *(const bf16x8*)&A1h[ac];
            if constexpr (DUAL)  a2 = *(const bf16x8*)&A2h[ac];
            #pragma unroll
            for (int nt = 0; nt < NT; ++nt) {
                const bf16x8 b1 = *(const bf16x8*)&Bs[(nt * 16 + col) * KC + kx];
                acc[nt] = __builtin_amdgcn_mfma_f32_16x16x32_bf16(a1, b1, acc[nt], 0, 0, 0);
                if constexpr (DUAL) {
                    const bf16x8 b2 = *(const bf16x8*)&Bs[GPM * 8 + (nt * 16 + col) * KC + kx];
                    acc[nt] = __builtin_amdgcn_mfma_f32_16x16x32_bf16(a2, b2, acc[nt], 0, 0, 0);
                }
            }
        }
    }

    #pragma unroll
    for (int nt = 0; nt < NT; ++nt) {
        const int c = nt * 16 + col;
        const float bb = bias[c];
        #pragma unroll
        for (int rr = 0; rr < 4; ++rr) {
            const long row = row0 + kg * 4 + rr;
            float o = acc[nt][rr] + bb;
            if constexpr (RELU) o = fmaxf(o, 0.f);
            if constexpr (OUT_BF16)
                ((unsigned short*)Cv)[row * N + c] = f2bf(o);
            else
                ((float*)Cv)[row * N + c] = o;
        }
    }
}

__global__ __launch_bounds__(256)
void scan1_k(const int* __restrict__ hist, int* __restrict__ offs,
             int* __restrict__ bsum, int n)
{
    __shared__ int sm[256];
    const int t = threadIdx.x;
    const int base = blockIdx.x * 1024 + t * 4;
    int4 v = make_int4(0, 0, 0, 0);
    if (base < n) v = *(const int4*)&hist[base];
    const int s = v.x + v.y + v.z + v.w;
    int val = s;
    sm[t] = val; __syncthreads();
    #pragma unroll
    for (int off = 1; off < 256; off <<= 1) {
        const int add = (t >= off) ? sm[t - off] : 0;
        __syncthreads();
        val += add;
        sm[t] = val;
        __syncthreads();
    }
    const int excl = val - s;
    if (base < n) {
        offs[base]     = excl;
        offs[base + 1] = excl + v.x;
        offs[base + 2] = excl + v.x + v.y;
        offs[base + 3] = excl + v.x + v.y + v.z;
    }
    if (t == 255) bsum[blockIdx.x] = val;
}

__global__ __launch_bounds__(512)
void scan2_k(int* __restrict__ bsum, int nb)
{
    __shared__ int sm[512];
    const int t = threadIdx.x;
    const int s = (t < nb) ? bsum[t] : 0;
    int val = s;
    sm[t] = val; __syncthreads();
    #pragma unroll
    for (int off = 1; off < 512; off <<= 1) {
        const int add = (t >= off) ? sm[t - off] : 0;
        __syncthreads();
        val += add;
        sm[t] = val;
        __syncthreads();
    }
    if (t < nb) bsum[t] = val - s;
}

__global__ __launch_bounds__(256)
void scan3_k(int* __restrict__ offs, const int* __restrict__ bsum, int etot)
{
    const int i = blockIdx.x * 256 + threadIdx.x;
    offs[i] += bsum[i >> 10];
    if (i == 0) offs[NTOT] = etot;               // sentinel
}

// atomic-free placement using precomputed rank
__global__ __launch_bounds__(256)
void place_k(CsrArgs a, const int* __restrict__ offs, const int* __restrict__ rank,
             int* __restrict__ ssrc)
{
    const int i = blockIdx.x * 256 + threadIdx.x;
    if (i >= a.etot) return;
    const int* dstp; const int* srcp; int e, hb;
    if (i < a.e0)       { dstp = a.dst0; srcp = a.src0; e = i;         hb = 0; }
    else if (i < a.e01) { dstp = a.dst1; srcp = a.src1; e = i - a.e0;  hb = N1c; }
    else                { dstp = a.dst2; srcp = a.src2; e = i - a.e01; hb = N1c + N2c; }
    const int g = hb + dstp[e];
    ssrc[offs[g] + rank[i]] = srcp[e];
}

// one wave per dst row; half-wave covers a 512B row via u16x8.
// Exact 16-edge batches (no mask), then one masked 8- or 4-load tail batch.
__global__ __launch_bounds__(256)
void agg_k(const unsigned short* __restrict__ h, const int* __restrict__ ssrc,
           const int* __restrict__ ob, unsigned short* __restrict__ agg, int n)
{
    const int w    = blockIdx.x * 4 + (threadIdx.x >> 6);
    const int lane = threadIdx.x & 63;
    if (w >= n) return;
    const int beg = ob[w];
    const int end = ob[w + 1];
    const int hf  = lane >> 5;
    const int co  = (lane & 31) * 8;

    float acc[8] = {0.f, 0.f, 0.f, 0.f, 0.f, 0.f, 0.f, 0.f};

    int j = beg;
    for (; j + 16 <= end; j += 16) {             // exact batches: no masking
        u16x8 v[8];
        #pragma unroll
        for (int q = 0; q < 8; ++q)
            v[q] = *(const u16x8*)&h[(size_t)ssrc[j + 2 * q + hf] * 256 + co];
        #pragma unroll
        for (int q = 0; q < 8; ++q)
            #pragma unroll
            for (int c = 0; c < 8; ++c) acc[c] += bf2f(v[q][c]);
    }
    const int rem = end - j;
    if (rem > 8) {                               // masked 8-load batch
        u16x8 v[8]; bool ok[8];
        #pragma unroll
        for (int q = 0; q < 8; ++q) {
            const int e = j + 2 * q + hf;
            ok[q] = (e < end);
            v[q] = *(const u16x8*)&h[(size_t)ssrc[ok[q] ? e : (end - 1)] * 256 + co];
        }
        #pragma unroll
        for (int q = 0; q < 8; ++q)
            #pragma unroll
            for (int c = 0; c < 8; ++c) acc[c] += ok[q] ? bf2f(v[q][c]) : 0.0f;
    } else if (rem > 0) {                        // masked 4-load batch
        u16x8 v[4]; bool ok[4];
        #pragma unroll
        for (int q = 0; q < 4; ++q) {
            const int e = j + 2 * q + hf;
            ok[q] = (e < end);
            v[q] = *(const u16x8*)&h[(size_t)ssrc[ok[q] ? e : (end - 1)] * 256 + co];
        }
        #pragma unroll
        for (int q = 0; q < 4; ++q)
            #pragma unroll
            for (int c = 0; c < 8; ++c) acc[c] += ok[q] ? bf2f(v[q][c]) : 0.0f;
    }

    #pragma unroll
    for (int c = 0; c < 8; ++c) acc[c] += __shfl_xor(acc[c], 32);

    if (hf == 0) {
        const float inv = 1.0f / fmaxf((float)(end - beg), 1.0f);
        u16x8 o;
        #pragma unroll
        for (int c = 0; c < 8; ++c) o[c] = f2bf(acc[c] * inv);
        *(u16x8*)&agg[(size_t)w * 256 + co] = o;
    }
}

extern "C" void kernel_launch(void* const* d_in, const int* in_sizes, int n_in,
                              void* d_out, int out_size, void* d_ws, size_t ws_size,
                              hipStream_t stream)
{
    const float* x    = (const float*)d_in[0];
    const int*   src0 = (const int*)d_in[1];
    const int*   dst0 = (const int*)d_in[2];
    const int*   src1 = (const int*)d_in[3];
    const int*   dst1 = (const int*)d_in[4];
    const int*   src2 = (const int*)d_in[5];
    const int*   dst2 = (const int*)d_in[6];
    const float* Wfc  = (const float*)d_in[10];
    const float* bfc  = (const float*)d_in[11];
    const float* Ws0  = (const float*)d_in[12];
    const float* Wn0  = (const float*)d_in[13];
    const float* b0   = (const float*)d_in[14];
    const float* Ws1  = (const float*)d_in[15];
    const float* Wn1  = (const float*)d_in[16];
    const float* b1   = (const float*)d_in[17];
    const float* Ws2  = (const float*)d_in[18];
    const float* Wn2  = (const float*)d_in[19];
    const float* b2   = (const float*)d_in[20];
    const int E0 = in_sizes[1], E1 = in_sizes[3], E2 = in_sizes[5];
    const int Etot = E0 + E1 + E2;

    char* ws = (char*)d_ws;
    unsigned short* h0   = (unsigned short*)ws;                    // 256 MiB
    unsigned short* h1   = (unsigned short*)(ws + (256ULL << 20)); // 128 MiB
    unsigned short* h2   = (unsigned short*)(ws + (384ULL << 20)); //  32 MiB
    unsigned short* agg  = (unsigned short*)(ws + (416ULL << 20)); // 128 MiB
    unsigned short* Wt   = (unsigned short*)(ws + (544ULL << 20)); //   1 MiB
    int*            hist = (int*)(ws + (545ULL << 20));            // 1.31 MiB
    int*            offs = (int*)(ws + (547ULL << 20));            // 1.31 MiB +1
    int*            bsum = (int*)(ws + (549ULL << 20));            //   2 KiB
    int*            ssrc = (int*)(ws + (550ULL << 20));            // 12.9 MiB
    int*            rank = (int*)(ws + (564ULL << 20));            // 12.9 MiB

    unsigned short* wfc = Wt;
    unsigned short* ws0 = Wt + 65536;
    unsigned short* wn0 = Wt + 131072;
    unsigned short* ws1 = Wt + 196608;
    unsigned short* wn1 = Wt + 262144;
    unsigned short* ws2 = Wt + 327680;
    unsigned short* wn2 = Wt + 344064;

    const dim3 blk(256);

    // 1) weights -> bf16 [N][K] + zero hist (fused)
    WPack wp;
    wp.w[0] = Wfc; wp.w[1] = Ws0; wp.w[2] = Wn0; wp.w[3] = Ws1; wp.w[4] = Wn1;
    wp.w[5] = Ws2; wp.w[6] = Wn2;
    wp.o[0] = wfc; wp.o[1] = ws0; wp.o[2] = wn0; wp.o[3] = ws1; wp.o[4] = wn1;
    wp.o[5] = ws2; wp.o[6] = wn2;
    wconv_all<<<dim3(1408 + 328), blk, 0, stream>>>(wp, hist);

    // 2) fused: FC GEMM + rank atomic pass (overlapped)
    CsrArgs ca;
    ca.src0 = src0; ca.dst0 = dst0; ca.src1 = src1; ca.dst1 = dst1;
    ca.src2 = src2; ca.dst2 = dst2;
    ca.e0 = E0; ca.e01 = E0 + E1; ca.etot = Etot;
    const int gemmBlocks = N0c / 128;                     // 4096
    const int rankBlocks = (Etot + 511) / 512;
    fc_rank_k<<<dim3(gemmBlocks + rankBlocks), dim3(512), 0, stream>>>(
        x, wfc, bfc, h0, ca, hist, rank, gemmBlocks);

    // 3) scan + place
    scan1_k<<<dim3(NTOT / 1024), blk, 0, stream>>>(hist, offs, bsum, NTOT);
    scan2_k<<<dim3(1), dim3(512), 0, stream>>>(bsum, NTOT / 1024);
    scan3_k<<<dim3(NTOT / 256), blk, 0, stream>>>(offs, bsum, Etot);
    place_k<<<dim3((Etot + 255) / 256), blk, 0, stream>>>(ca, offs, rank, ssrc);

    // 4) layer 0
    agg_k<<<dim3(N1c / 4), blk, 0, stream>>>(h0, ssrc, offs, agg, N1c);
    gemm2<16, 64, true, true, false, true><<<dim3(N1c / 128), dim3(512), 0, stream>>>(
        h0, agg, ws0, wn0, b0, h1);

    // 5) layer 1
    agg_k<<<dim3(N2c / 4), blk, 0, stream>>>(h1, ssrc, offs + N1c, agg, N2c);
    gemm2<16, 64, true, true, false, true><<<dim3(N2c / 128), dim3(512), 0, stream>>>(
        h1, agg, ws1, wn1, b1, h2);

    // 6) layer 2
    agg_k<<<dim3(N3c / 4), blk, 0, stream>>>(h2, ssrc, offs + N1c + N2c, agg, N3c);
    gemm2<4, 256, true, false, false, false><<<dim3(N3c / 128), dim3(512), 0, stream>>>(
        h2, agg, ws2, wn2, b2, (float*)d_out);
}